// Round 4
// baseline (459.098 us; speedup 1.0000x reference)
//
#include <hip/hip_runtime.h>

// Problem: ExodusModel_8564164788248
// inp: (8,2,256,256,64) f32, w0: (4,2,7,7), w1: (8,4,7,7), wl: (2,128)
// out: (8,2,64) f32
//
// Workspace layout (floats):
//   pooled0 : (8,2,64,64,64)  = 4,194,304   @ 0
//   pooled1 : (8,4,16,16,64)  =   524,288   @ 12,582,912
//   h1      : (8,8,16,16,64)  = 1,048,576   @ 13,107,200  (s1 never stored)
//   feat    : (8,128,64)      =    65,536   @ 14,155,776
//   (h0 is never materialized: conv0 -> IAF0 -> pool1 is fused via LDS)

#define OFF_P0   0
#define OFF_P1   12582912
#define OFF_H1   13107200
#define OFF_FT   14155776

typedef float f32x4 __attribute__((ext_vector_type(4)));

// ---------------------------------------------------------------------------
// K1: avgpool 4x4 on raw input. (n,c,256,256,t) -> (n,c,64,64,t)
// float4 on stride-1 t axis; fp64 accumulate (exact /16). HBM-floor bound.
// Non-temporal loads: the 268 MB input is read-once streaming — keep it from
// evicting pooled0 (which K2 re-reads) out of L2/L3.
__global__ __launch_bounds__(256) void pool0_kernel(
        const float* __restrict__ inp, float* __restrict__ out) {
    int tid = blockIdx.x * blockDim.x + threadIdx.x;   // 1,048,576 threads
    int t4 = tid & 15;
    int px = (tid >> 4) & 63;
    int py = (tid >> 10) & 63;
    int nc = tid >> 16;                                // n*2+c, 0..15
    const float* base = inp + (size_t)nc * 4194304 + (size_t)t4 * 4;
    int y0 = py * 4, x0 = px * 4;
    double a0 = 0, a1 = 0, a2 = 0, a3 = 0;
    #pragma unroll
    for (int dy = 0; dy < 4; ++dy) {
        const float* row = base + ((size_t)(y0 + dy) * 256 + x0) * 64;
        #pragma unroll
        for (int dx = 0; dx < 4; ++dx) {
            const f32x4 v = __builtin_nontemporal_load(
                (const f32x4*)(row + dx * 64));
            a0 += (double)v.x; a1 += (double)v.y;
            a2 += (double)v.z; a3 += (double)v.w;
        }
    }
    float4 o = make_float4((float)(a0 * 0.0625), (float)(a1 * 0.0625),
                           (float)(a2 * 0.0625), (float)(a3 * 0.0625));
    ((float4*)out)[tid] = o;
}

// ---------------------------------------------------------------------------
// K2: FUSED conv0 + IAF0 + pool1. h0 never hits HBM.
// Grid = (n 8)(pyo 16)(pxb 8) = 1024 blocks x 256 threads, 32 KB LDS.
// Tile: oc 0..3, py = pyo*4..+3, px = pxb*8..+7, t 0..63.
//
// Phase 1 (conv): thread = t4(16) x pxl(8) x pp(2); computes 2 adjacent py
// rows x 4 oc x 4 t, fp64 acc, per-output tap order (ic,ky,kx) ascending ==
// previous conv0 => bit-identical h0 values. Results go to LDS with a
// (t+p)&63 rotation: bank=(t+p)&31 => 2-way (free) in both phases.
// Phase 2 (IAF+pool): 128 threads scan their stream (exact reference fp32
// sequence), byte-pack spikes 4/u32 (sums<=16 fit a byte), shfl_xor(1,2,8,16)
// over (dx,dy), coalesced float4 stores of pooled1.
__global__ __launch_bounds__(256) void conv0_iaf0_pool1_kernel(
        const float* __restrict__ pooled0, const float* __restrict__ w0,
        float* __restrict__ pooled1) {
    __shared__ double w[392];                          // [oc*98 + ic*49 + ky*7 + kx]
    __shared__ float tile[8192];                       // [p 128][t 64], t rotated by p

    for (int i = threadIdx.x; i < 392; i += blockDim.x) w[i] = (double)w0[i];

    int b   = blockIdx.x;                              // (n 8)(pyo 16)(pxb 8)
    int pxb = b & 7;
    int pyo = (b >> 3) & 15;
    int n   = b >> 7;

    int tid = threadIdx.x;
    int t4  = tid & 15;
    int pxl = (tid >> 4) & 7;
    int pp  = tid >> 7;                                // 0..1
    int px  = pxb * 8 + pxl;
    int py0 = pyo * 4 + pp * 2;                        // rows py0, py0+1

    __syncthreads();                                   // weights ready

    double acc[4][2][4] = {};                          // [oc][row][t]
    for (int ic = 0; ic < 2; ++ic) {
        const float* in_c = pooled0 + (size_t)(n * 2 + ic) * 262144 + t4 * 4;
        const double* wic = w + ic * 49;               // + oc*98 + ky*7 + kx
        #pragma unroll
        for (int r = 0; r < 8; ++r) {                  // iy = py0-3+r
            int iy = py0 - 3 + r;
            if (iy < 0 || iy >= 64) continue;
            const float* in_row = in_c + (size_t)iy * 4096;
            #pragma unroll
            for (int kx = 0; kx < 7; ++kx) {
                int ix = px + kx - 3;
                if (ix < 0 || ix >= 64) continue;
                float4 v = *(const float4*)(in_row + ix * 64);
                if (r <= 6) {                          // ky = r for row py0
                    #pragma unroll
                    for (int oc = 0; oc < 4; ++oc) {
                        double wd = wic[oc * 98 + r * 7 + kx];
                        acc[oc][0][0] += (double)v.x * wd;
                        acc[oc][0][1] += (double)v.y * wd;
                        acc[oc][0][2] += (double)v.z * wd;
                        acc[oc][0][3] += (double)v.w * wd;
                    }
                }
                if (r >= 1) {                          // ky = r-1 for row py0+1
                    #pragma unroll
                    for (int oc = 0; oc < 4; ++oc) {
                        double wd = wic[oc * 98 + (r - 1) * 7 + kx];
                        acc[oc][1][0] += (double)v.x * wd;
                        acc[oc][1][1] += (double)v.y * wd;
                        acc[oc][1][2] += (double)v.z * wd;
                        acc[oc][1][3] += (double)v.w * wd;
                    }
                }
            }
        }
    }
    // scatter to LDS, rotated: idx = p*64 + (t+p)&63
    #pragma unroll
    for (int oc = 0; oc < 4; ++oc) {
        #pragma unroll
        for (int row = 0; row < 2; ++row) {
            int p = oc * 32 + (pp * 2 + row) * 8 + pxl;
            #pragma unroll
            for (int j = 0; j < 4; ++j) {
                int tt = t4 * 4 + j;
                tile[p * 64 + ((tt + p) & 63)] = (float)acc[oc][row][j];
            }
        }
    }
    __syncthreads();

    if (tid < 128) {
        int p   = tid;                                 // oc(2b at 5)|pyl(2b at 3)|pxl(3b)
        int oc  = p >> 5;
        int pxo = (p >> 2) & 1;
        float v = 0.f;
        unsigned int sp[16];
        const float* tp = tile + p * 64;
        #pragma unroll
        for (int i = 0; i < 16; ++i) {
            unsigned int wd = 0;
            #pragma unroll
            for (int j = 0; j < 4; ++j) {
                int t = i * 4 + j;
                float x = tp[(t + p) & 63];
                v += x;
                unsigned int s_ = (v >= 1.f) ? 1u : 0u;
                v -= (float)s_;
                wd += s_ << (8 * j);
            }
            sp[i] = wd;
        }
        // pool over dx (bits 0,1) and dy (bits 3,4); bytes can't carry
        #pragma unroll
        for (int i = 0; i < 16; ++i) {
            sp[i] += __shfl_xor(sp[i], 1);
            sp[i] += __shfl_xor(sp[i], 2);
            sp[i] += __shfl_xor(sp[i], 8);
            sp[i] += __shfl_xor(sp[i], 16);
        }
        int i = (p & 3) | (((p >> 3) & 3) << 2);       // member index 0..15
        unsigned int s = sp[i];
        float4 o = make_float4((float)(s & 255u)         * 0.0625f,
                               (float)((s >> 8)  & 255u) * 0.0625f,
                               (float)((s >> 16) & 255u) * 0.0625f,
                               (float)((s >> 24) & 255u) * 0.0625f);
        float* outp = pooled1 +
            (((size_t)(n * 4 + oc) * 16 + pyo) * 16 + (pxb * 2 + pxo)) * 64 + i * 4;
        *(float4*)outp = o;
    }
}

// ---------------------------------------------------------------------------
// K3 v2: conv7 pad3, ic=4 -> oc=8 on (8,4,16,16,t). fp64 accumulate, same tap
// order (ic,ky,kx ascending) as before => bit-identical h1.
// Restructured vs v1: each thread computes 4 t-values (float4 input load) x
// 4 oc (oc-group split across threads). Per tap: 1 float4 load + 4
// ds_read_b64 + 16 fp64 FMA — weight-LDS traffic /4, global load count /4 vs
// v1 (which did 8 ds_read_b64 + 1 scalar load + 8 FMA per tap per t).
// Grid: 65,536 threads = 256 blocks x 256.
__global__ __launch_bounds__(256) void conv1_kernel(
        const float* __restrict__ pooled1,
        const float* __restrict__ w1,
        float* __restrict__ h1) {
    __shared__ double w[1568];                         // (8,4,7,7)
    for (int i = threadIdx.x; i < 1568; i += blockDim.x) w[i] = (double)w1[i];
    __syncthreads();

    int tid = blockIdx.x * blockDim.x + threadIdx.x;   // 65,536 threads
    int t4 = tid & 15;                                 // 4 t per thread
    int px = (tid >> 4) & 15;
    int py = (tid >> 8) & 15;
    int og = (tid >> 12) & 1;                          // oc group: og*4 .. og*4+3
    int n  = tid >> 13;                                // 0..7

    double acc[4][4] = {};                             // [oc4][t j]

    for (int ic = 0; ic < 4; ++ic) {
        const float* in_c = pooled1 + (size_t)(n * 4 + ic) * 16384 + t4 * 4;
        const double* wic = w + (size_t)og * 4 * 196 + ic * 49;  // + oc4*196 + ky*7 + kx
        #pragma unroll
        for (int ky = 0; ky < 7; ++ky) {
            int iy = py + ky - 3;
            if (iy < 0 || iy >= 16) continue;
            const float* in_row = in_c + (size_t)iy * 1024;
            #pragma unroll
            for (int kx = 0; kx < 7; ++kx) {
                int ix = px + kx - 3;
                if (ix < 0 || ix >= 16) continue;
                float4 v = *(const float4*)(in_row + ix * 64);
                #pragma unroll
                for (int oc4 = 0; oc4 < 4; ++oc4) {
                    double wd = wic[oc4 * 196 + ky * 7 + kx];
                    acc[oc4][0] += (double)v.x * wd;
                    acc[oc4][1] += (double)v.y * wd;
                    acc[oc4][2] += (double)v.z * wd;
                    acc[oc4][3] += (double)v.w * wd;
                }
            }
        }
    }
    size_t ob = (size_t)n * 131072 + (size_t)(og * 4) * 16384
              + (size_t)py * 1024 + px * 64 + t4 * 4;
    #pragma unroll
    for (int oc4 = 0; oc4 < 4; ++oc4) {
        float4 o = make_float4((float)acc[oc4][0], (float)acc[oc4][1],
                               (float)acc[oc4][2], (float)acc[oc4][3]);
        *(float4*)(h1 + ob + (size_t)oc4 * 16384) = o;
    }
}

// ---------------------------------------------------------------------------
// K4: fused IAF1 + avgpool4 -> feat(n,128,t). Spikes never hit memory.
__global__ __launch_bounds__(256) void iaf1_pool2_kernel(
        const float* __restrict__ h1, float* __restrict__ feat) {
    int b = blockIdx.x;                                // 64 = (n 8)(c 8)
    int c = b & 7;
    int n = b >> 3;
    int tid = threadIdx.x;
    int dx  = tid & 3;
    int dy  = (tid >> 2) & 3;
    int q   = tid >> 4;                                // 0..15 = pyo*4+pxo
    int pyo = q >> 2;
    int pxo = q & 3;
    int py  = pyo * 4 + dy;
    int px  = pxo * 4 + dx;

    const float4* p = (const float4*)(h1 +
        (((size_t)(n * 8 + c) * 16 + py) * 16 + px) * 64);

    float v = 0.f;
    unsigned int sp[16];
    #pragma unroll
    for (int i = 0; i < 16; ++i) {
        float4 x = p[i];
        unsigned int w = 0;
        #define STEP(j, e)                                                    \
        {   v += x.e;                                                         \
            unsigned int s_ = (v >= 1.f) ? 1u : 0u;                           \
            v -= (float)s_;                                                   \
            w += s_ << (8 * j); }
        STEP(0, x) STEP(1, y) STEP(2, z) STEP(3, w)
        #undef STEP
        sp[i] = w;
    }
    #pragma unroll
    for (int i = 0; i < 16; ++i) {
        sp[i] += __shfl_xor(sp[i], 1);
        sp[i] += __shfl_xor(sp[i], 2);
        sp[i] += __shfl_xor(sp[i], 4);
        sp[i] += __shfl_xor(sp[i], 8);
    }
    int i = tid & 15;
    unsigned int s = sp[i];
    float4 o = make_float4((float)(s & 255u)         * 0.0625f,
                           (float)((s >> 8)  & 255u) * 0.0625f,
                           (float)((s >> 16) & 255u) * 0.0625f,
                           (float)((s >> 24) & 255u) * 0.0625f);
    int f = c * 16 + q;
    *(float4*)(feat + ((size_t)n * 128 + f) * 64 + i * 4) = o;
}

// ---------------------------------------------------------------------------
// K5: linear. out(n,j,t) = sum_f wl[j,f] * feat[n,f,t], fp64 acc, f ascending
// => bit-identical out.
__global__ __launch_bounds__(64) void linear_kernel(
        const float* __restrict__ feat, const float* __restrict__ wl,
        float* __restrict__ out) {
    int tid = blockIdx.x * 64 + threadIdx.x;           // 1024 threads
    int t = tid & 63;
    int j = (tid >> 6) & 1;
    int n = tid >> 7;
    const float* fp = feat + (size_t)n * 128 * 64 + t;
    const float* wp = wl + j * 128;
    double acc = 0.0;
    for (int f = 0; f < 128; ++f)
        acc += (double)wp[f] * (double)fp[(size_t)f * 64];
    out[(size_t)(n * 2 + j) * 64 + t] = (float)acc;
}

// ---------------------------------------------------------------------------
extern "C" void kernel_launch(void* const* d_in, const int* in_sizes, int n_in,
                              void* d_out, int out_size, void* d_ws, size_t ws_size,
                              hipStream_t stream) {
    const float* inp = (const float*)d_in[0];
    const float* w0  = (const float*)d_in[1];
    const float* w1  = (const float*)d_in[2];
    const float* wl  = (const float*)d_in[3];
    float* out = (float*)d_out;
    float* ws  = (float*)d_ws;

    float* pooled0 = ws + OFF_P0;
    float* pooled1 = ws + OFF_P1;
    float* h1      = ws + OFF_H1;
    float* feat    = ws + OFF_FT;

    pool0_kernel<<<4096, 256, 0, stream>>>(inp, pooled0);
    conv0_iaf0_pool1_kernel<<<1024, 256, 0, stream>>>(pooled0, w0, pooled1);
    conv1_kernel<<<256, 256, 0, stream>>>(pooled1, w1, h1);
    iaf1_pool2_kernel<<<64, 256, 0, stream>>>(h1, feat);
    linear_kernel<<<16, 64, 0, stream>>>(feat, wl, out);
}